// Round 3
// baseline (130.017 us; speedup 1.0000x reference)
//
#include <hip/hip_runtime.h>
#include <hip/hip_bf16.h>

#define D 32
#define FACTOR (-1.0f / 128.0f)   // -1/(2*8^2)
#define LOG2E  1.44269504088896340736f

typedef __attribute__((ext_vector_type(8)))  short bf16x8;
typedef __attribute__((ext_vector_type(16))) float f32x16;
typedef __attribute__((ext_vector_type(4)))  float f32x4;

#if __has_builtin(__builtin_amdgcn_exp2f)
#define EXP2(x) __builtin_amdgcn_exp2f(x)
#else
#define EXP2(x) exp2f(x)
#endif

__device__ __forceinline__ ushort bfr(float x) {
    __hip_bfloat16 h = __float2bfloat16(x);     // RNE
    return *reinterpret_cast<ushort*>(&h);
}
__device__ __forceinline__ float bf2f(ushort u) {
    uint w = ((uint)u) << 16;
    return *reinterpret_cast<float*>(&w);
}
__device__ __forceinline__ uint pk2(float a, float b) {
    return (uint)bfr(a) | ((uint)bfr(b) << 16);
}

// ---------------------------------------------------------------------------
// Prep: bf16 copies of X and Y, transposed yT[d][m], x2/y2 from ROUNDED
// values. 4 lanes per row, 8 elements per lane -> (N+M)*4 threads.
// ---------------------------------------------------------------------------
__global__ __launch_bounds__(256) void msk_prep(const float* __restrict__ X,
                                                const float* __restrict__ Y,
                                                ushort* __restrict__ Xb,
                                                ushort* __restrict__ Yb,
                                                ushort* __restrict__ yT,
                                                float* __restrict__ x2,
                                                float* __restrict__ y2,
                                                int N, int M) {
    const int t = blockIdx.x * 256 + threadIdx.x;
    const int i = t >> 2;            // logical row over [0, N+M)
    const int c = t & 3;             // 8-elem chunk within the row
    if (i >= N + M) return;
    const bool isX = (i < N);
    const int r = isX ? i : i - N;
    const float* src = (isX ? X : Y) + (size_t)r * D + c * 8;

    float4 va = *reinterpret_cast<const float4*>(src);
    float4 vb = *reinterpret_cast<const float4*>(src + 4);
    float f[8] = {va.x, va.y, va.z, va.w, vb.x, vb.y, vb.z, vb.w};

    ushort u[8];
    float s = 0.f;
#pragma unroll
    for (int k = 0; k < 8; ++k) {
        u[k] = bfr(f[k]);
        float g = bf2f(u[k]);
        s = fmaf(g, g, s);
    }
    // sum over the 4 lanes of this row (lanes 4k..4k+3)
    s += __shfl_xor(s, 1);
    s += __shfl_xor(s, 2);

    uint w[4];
#pragma unroll
    for (int q = 0; q < 4; ++q) w[q] = (uint)u[2 * q] | ((uint)u[2 * q + 1] << 16);

    ushort* dstrow = (isX ? Xb : Yb) + (size_t)r * D + c * 8;
    *reinterpret_cast<uint4*>(dstrow) = *reinterpret_cast<const uint4*>(w);

    if (c == 0) (isX ? x2 : y2)[r] = s;

    if (!isX) {
#pragma unroll
        for (int k = 0; k < 8; ++k)
            yT[(size_t)(c * 8 + k) * M + r] = u[k];
    }
}

// ---------------------------------------------------------------------------
// Main fused kernel (structure verified in round 2):
//   GEMM1 (swapped): S^T = Y_tile . X_tile^T via 2x mfma_32x32x16_bf16
//   exp in log2 domain; GEMM2: nom += K . Y via packed-bf16 A-frags whose
//   per-lane m-order is absorbed into the yT B-operand addressing.
// Partials: pnom[s][N][32] (coalesced), pden[s][N].
// ---------------------------------------------------------------------------
__global__ __launch_bounds__(256) void msk_main(const ushort* __restrict__ Xb,
                                                const ushort* __restrict__ Yb,
                                                const ushort* __restrict__ yT,
                                                const float* __restrict__ x2,
                                                const float* __restrict__ y2,
                                                float* __restrict__ pnom,
                                                float* __restrict__ pden,
                                                int N, int M, int chunk) {
    const int lane = threadIdx.x & 63;
    const int wid  = threadIdx.x >> 6;
    const int h    = lane >> 5;
    const int ln   = lane & 31;
    const int n0   = blockIdx.x * 128 + wid * 32;
    const int m0b  = blockIdx.y * chunk;

    // x B-fragments: element (h,j) <-> d = 16*ks + 8h + j
    const ushort* xrow = Xb + (size_t)(n0 + ln) * D + h * 8;
    const bf16x8 xf0 = *reinterpret_cast<const bf16x8*>(xrow);
    const bf16x8 xf1 = *reinterpret_cast<const bf16x8*>(xrow + 16);

    const float F2  = FACTOR * LOG2E;
    const float C2  = -2.0f * F2;
    const float xb2 = x2[n0 + ln] * F2;

    f32x16 nom = {};
    float den = 0.f;

    for (int m0 = m0b; m0 < m0b + chunk; m0 += 32) {
        const ushort* yrow = Yb + (size_t)(m0 + ln) * D + h * 8;
        bf16x8 yf0 = *reinterpret_cast<const bf16x8*>(yrow);
        bf16x8 yf1 = *reinterpret_cast<const bf16x8*>(yrow + 16);
        f32x16 s = {};
        s = __builtin_amdgcn_mfma_f32_32x32x16_bf16(yf0, xf0, s, 0, 0, 0);
        s = __builtin_amdgcn_mfma_f32_32x32x16_bf16(yf1, xf1, s, 0, 0, 0);
        // s reg r: m = m0 + (r&3) + 8*(r>>2) + 4h ; n = n0 + ln

        uint pw[8];
#pragma unroll
        for (int r4 = 0; r4 < 4; ++r4) {
            f32x4 yv = *reinterpret_cast<const f32x4*>(y2 + m0 + r4 * 8 + h * 4);
            float kq[4];
#pragma unroll
            for (int q = 0; q < 4; ++q) {
                float base = fmaf(yv[q], F2, xb2);
                kq[q] = EXP2(fmaf(s[r4 * 4 + q], C2, base));
            }
            den += (kq[0] + kq[1]) + (kq[2] + kq[3]);
            pw[r4 * 2 + 0] = pk2(kq[0], kq[1]);
            pw[r4 * 2 + 1] = pk2(kq[2], kq[3]);
        }
        union Fu { uint u[4]; bf16x8 v; };
        Fu pa0, pa1;
        pa0.u[0] = pw[0]; pa0.u[1] = pw[1]; pa0.u[2] = pw[2]; pa0.u[3] = pw[3];
        pa1.u[0] = pw[4]; pa1.u[1] = pw[5]; pa1.u[2] = pw[6]; pa1.u[3] = pw[7];

        // GEMM2 B-frags: element (h,j) <-> m = 16ks + 8*(j>>2) + 4h + (j&3)
        const ushort* ytr = yT + (size_t)ln * M + m0 + h * 4;
        Fu b0, b1;
        *reinterpret_cast<uint2*>(&b0.u[0]) = *reinterpret_cast<const uint2*>(ytr);
        *reinterpret_cast<uint2*>(&b0.u[2]) = *reinterpret_cast<const uint2*>(ytr + 8);
        *reinterpret_cast<uint2*>(&b1.u[0]) = *reinterpret_cast<const uint2*>(ytr + 16);
        *reinterpret_cast<uint2*>(&b1.u[2]) = *reinterpret_cast<const uint2*>(ytr + 24);

        nom = __builtin_amdgcn_mfma_f32_32x32x16_bf16(pa0.v, b0.v, nom, 0, 0, 0);
        nom = __builtin_amdgcn_mfma_f32_32x32x16_bf16(pa1.v, b1.v, nom, 0, 0, 0);
    }

    den += __shfl_xor(den, 32);   // halves hold disjoint m partials for same n

    const size_t base = (size_t)blockIdx.y * N;
#pragma unroll
    for (int r = 0; r < 16; ++r) {
        int row = (r & 3) + 8 * (r >> 2) + 4 * h;            // n offset
        pnom[(base + n0 + row) * 32 + ln] = nom[r];          // d = ln
    }
    if (h == 0) pden[base + n0 + ln] = den;
}

// ---------------------------------------------------------------------------
// Reduce over m-chunks and divide. pnom reads are fully coalesced; pden
// reads are same-address broadcasts within each 32-thread group.
// ---------------------------------------------------------------------------
__global__ __launch_bounds__(256) void msk_reduce(const float* __restrict__ pnom,
                                                  const float* __restrict__ pden,
                                                  float* __restrict__ out,
                                                  int N, int S) {
    const int t = blockIdx.x * blockDim.x + threadIdx.x;
    if (t >= N * 32) return;
    const int n = t >> 5;
    float nom = 0.f, den = 0.f;
    for (int s = 0; s < S; ++s) {
        nom += pnom[(size_t)s * N * 32 + t];
        den += pden[(size_t)s * N + n];
    }
    out[t] = nom / den;
}

// ---------------------------------------------------------------------------
extern "C" void kernel_launch(void* const* d_in, const int* in_sizes, int n_in,
                              void* d_out, int out_size, void* d_ws, size_t ws_size,
                              hipStream_t stream) {
    const float* X = (const float*)d_in[0];
    const float* Y = (const float*)d_in[1];
    float* out     = (float*)d_out;

    const int N = in_sizes[0] / D;   // 8192
    const int M = in_sizes[1] / D;   // 8192

    char* p = (char*)d_ws;
    ushort* Xb = (ushort*)p; p += (size_t)N * D * sizeof(ushort);
    ushort* Yb = (ushort*)p; p += (size_t)M * D * sizeof(ushort);
    ushort* yT = (ushort*)p; p += (size_t)M * D * sizeof(ushort);
    float*  x2 = (float*)p;  p += (size_t)N * sizeof(float);
    float*  y2 = (float*)p;  p += (size_t)M * sizeof(float);
    size_t used = (size_t)(p - (char*)d_ws);
    used = (used + 255) & ~(size_t)255;

    // per chunk: nom N*32 floats + den N floats
    const size_t per_s = (size_t)N * 33 * sizeof(float);
    int S = 32;
    while (S > 1 && used + (size_t)S * per_s > ws_size) S >>= 1;
    const int chunk = M / S;

    float* pnom = (float*)((char*)d_ws + used);
    float* pden = pnom + (size_t)S * N * 32;

    msk_prep<<<dim3(((N + M) * 4 + 255) / 256), dim3(256), 0, stream>>>(
        X, Y, Xb, Yb, yT, x2, y2, N, M);

    msk_main<<<dim3(N / 128, S), dim3(256), 0, stream>>>(
        Xb, Yb, yT, x2, y2, pnom, pden, N, M, chunk);

    msk_reduce<<<dim3((N * 32 + 255) / 256), dim3(256), 0, stream>>>(
        pnom, pden, out, N, S);
}

// Round 4
// 116.892 us; speedup vs baseline: 1.1123x; 1.1123x over previous
//
#include <hip/hip_runtime.h>
#include <hip/hip_bf16.h>

#define D 32
#define FACTOR (-1.0f / 128.0f)   // -1/(2*8^2)
#define LOG2E  1.44269504088896340736f

typedef __attribute__((ext_vector_type(8)))  short bf16x8;
typedef __attribute__((ext_vector_type(16))) float f32x16;
typedef __attribute__((ext_vector_type(4)))  float f32x4;

#if __has_builtin(__builtin_amdgcn_exp2f)
#define EXP2(x) __builtin_amdgcn_exp2f(x)
#else
#define EXP2(x) exp2f(x)
#endif

__device__ __forceinline__ ushort bfr(float x) {
    __hip_bfloat16 h = __float2bfloat16(x);     // RNE -> v_cvt_pk path
    return *reinterpret_cast<ushort*>(&h);
}
__device__ __forceinline__ float bf2f(ushort u) {
    uint w = ((uint)u) << 16;
    return *reinterpret_cast<float*>(&w);
}
__device__ __forceinline__ uint pk2(float a, float b) {
    return (uint)bfr(a) | ((uint)bfr(b) << 16);
}

// ---------------------------------------------------------------------------
// Prep: bf16 copies of X and Y, transposed yT[d][m], x2/y2 from ROUNDED
// values. 4 lanes per row, 8 elements per lane.
// ---------------------------------------------------------------------------
__global__ __launch_bounds__(256) void msk_prep(const float* __restrict__ X,
                                                const float* __restrict__ Y,
                                                ushort* __restrict__ Xb,
                                                ushort* __restrict__ Yb,
                                                ushort* __restrict__ yT,
                                                float* __restrict__ x2,
                                                float* __restrict__ y2,
                                                int N, int M) {
    const int t = blockIdx.x * 256 + threadIdx.x;
    const int i = t >> 2;
    const int c = t & 3;
    if (i >= N + M) return;
    const bool isX = (i < N);
    const int r = isX ? i : i - N;
    const float* src = (isX ? X : Y) + (size_t)r * D + c * 8;

    float4 va = *reinterpret_cast<const float4*>(src);
    float4 vb = *reinterpret_cast<const float4*>(src + 4);
    float f[8] = {va.x, va.y, va.z, va.w, vb.x, vb.y, vb.z, vb.w};

    ushort u[8];
    float s = 0.f;
#pragma unroll
    for (int k = 0; k < 8; ++k) {
        u[k] = bfr(f[k]);
        float g = bf2f(u[k]);
        s = fmaf(g, g, s);
    }
    s += __shfl_xor(s, 1);
    s += __shfl_xor(s, 2);

    uint w[4];
#pragma unroll
    for (int q = 0; q < 4; ++q) w[q] = (uint)u[2 * q] | ((uint)u[2 * q + 1] << 16);

    ushort* dstrow = (isX ? Xb : Yb) + (size_t)r * D + c * 8;
    *reinterpret_cast<uint4*>(dstrow) = *reinterpret_cast<const uint4*>(w);

    if (c == 0) (isX ? x2 : y2)[r] = s;

    if (!isX) {
#pragma unroll
        for (int k = 0; k < 8; ++k)
            yT[(size_t)(c * 8 + k) * M + r] = u[k];
    }
}

// ---------------------------------------------------------------------------
// Main fused kernel. Block = 4 waves sharing one 32-n tile; each wave takes
// a quarter of this block's m-chunk and runs a 2-way-unrolled (64 m / iter)
// MFMA->exp->MFMA pipeline (two independent chains for ILP). Block-level
// LDS reduction then writes pnom[s][N][32] (coalesced float4) + pden[s][N].
// ---------------------------------------------------------------------------
__global__ __launch_bounds__(256) void msk_main(const ushort* __restrict__ Xb,
                                                const ushort* __restrict__ Yb,
                                                const ushort* __restrict__ yT,
                                                const float* __restrict__ x2,
                                                const float* __restrict__ y2,
                                                float* __restrict__ pnom,
                                                float* __restrict__ pden,
                                                int N, int M, int chunk) {
    __shared__ float lnom[4096];
    __shared__ float lden[128];

    const int lane = threadIdx.x & 63;
    const int wid  = threadIdx.x >> 6;
    const int h    = lane >> 5;
    const int ln   = lane & 31;
    const int n0   = blockIdx.x * 32;
    const int mq   = chunk >> 2;                      // per-wave m length
    const int mw0  = blockIdx.y * chunk + wid * mq;

    // x B-fragments: element (h,j) <-> d = 16*ks + 8h + j
    const ushort* xrow = Xb + (size_t)(n0 + ln) * D + h * 8;
    const bf16x8 xf0 = *reinterpret_cast<const bf16x8*>(xrow);
    const bf16x8 xf1 = *reinterpret_cast<const bf16x8*>(xrow + 16);

    const float F2  = FACTOR * LOG2E;
    const float C2  = -2.0f * F2;
    const float xb2 = x2[n0 + ln] * F2;

    f32x16 nom = {};
    float den = 0.f;

    union Fu { uint u[4]; bf16x8 v; };

    auto expack = [&](const f32x16& s, int m0, uint* pw) {
#pragma unroll
        for (int r4 = 0; r4 < 4; ++r4) {
            f32x4 yv = *reinterpret_cast<const f32x4*>(y2 + m0 + r4 * 8 + h * 4);
            float kq[4];
#pragma unroll
            for (int q = 0; q < 4; ++q)
                kq[q] = EXP2(fmaf(s[r4 * 4 + q], C2, fmaf(yv[q], F2, xb2)));
            den += (kq[0] + kq[1]) + (kq[2] + kq[3]);
            pw[r4 * 2 + 0] = pk2(kq[0], kq[1]);
            pw[r4 * 2 + 1] = pk2(kq[2], kq[3]);
        }
    };

    for (int m0 = mw0; m0 < mw0 + mq; m0 += 64) {
        // ---- tile A (m0) and tile B (m0+32): issue all loads up front
        const ushort* ya = Yb + (size_t)(m0 + ln) * D + h * 8;
        const ushort* yb = ya + 32 * D;
        bf16x8 af0 = *reinterpret_cast<const bf16x8*>(ya);
        bf16x8 af1 = *reinterpret_cast<const bf16x8*>(ya + 16);
        bf16x8 bf0 = *reinterpret_cast<const bf16x8*>(yb);
        bf16x8 bf1 = *reinterpret_cast<const bf16x8*>(yb + 16);

        const ushort* ytr = yT + (size_t)ln * M + m0 + h * 4;
        Fu bA0, bA1, bB0, bB1;
        *reinterpret_cast<uint2*>(&bA0.u[0]) = *reinterpret_cast<const uint2*>(ytr);
        *reinterpret_cast<uint2*>(&bA0.u[2]) = *reinterpret_cast<const uint2*>(ytr + 8);
        *reinterpret_cast<uint2*>(&bA1.u[0]) = *reinterpret_cast<const uint2*>(ytr + 16);
        *reinterpret_cast<uint2*>(&bA1.u[2]) = *reinterpret_cast<const uint2*>(ytr + 24);
        *reinterpret_cast<uint2*>(&bB0.u[0]) = *reinterpret_cast<const uint2*>(ytr + 32);
        *reinterpret_cast<uint2*>(&bB0.u[2]) = *reinterpret_cast<const uint2*>(ytr + 40);
        *reinterpret_cast<uint2*>(&bB1.u[0]) = *reinterpret_cast<const uint2*>(ytr + 48);
        *reinterpret_cast<uint2*>(&bB1.u[2]) = *reinterpret_cast<const uint2*>(ytr + 56);

        f32x16 sA = {}, sB = {};
        sA = __builtin_amdgcn_mfma_f32_32x32x16_bf16(af0, xf0, sA, 0, 0, 0);
        sB = __builtin_amdgcn_mfma_f32_32x32x16_bf16(bf0, xf0, sB, 0, 0, 0);
        sA = __builtin_amdgcn_mfma_f32_32x32x16_bf16(af1, xf1, sA, 0, 0, 0);
        sB = __builtin_amdgcn_mfma_f32_32x32x16_bf16(bf1, xf1, sB, 0, 0, 0);
        // s reg r: m = m0 + (r&3) + 8*(r>>2) + 4h ; n = n0 + ln

        uint pwA[8], pwB[8];
        expack(sA, m0, pwA);
        expack(sB, m0 + 32, pwB);

        Fu paA0, paA1, paB0, paB1;
#pragma unroll
        for (int q = 0; q < 4; ++q) {
            paA0.u[q] = pwA[q]; paA1.u[q] = pwA[q + 4];
            paB0.u[q] = pwB[q]; paB1.u[q] = pwB[q + 4];
        }

        nom = __builtin_amdgcn_mfma_f32_32x32x16_bf16(paA0.v, bA0.v, nom, 0, 0, 0);
        nom = __builtin_amdgcn_mfma_f32_32x32x16_bf16(paA1.v, bA1.v, nom, 0, 0, 0);
        nom = __builtin_amdgcn_mfma_f32_32x32x16_bf16(paB0.v, bB0.v, nom, 0, 0, 0);
        nom = __builtin_amdgcn_mfma_f32_32x32x16_bf16(paB1.v, bB1.v, nom, 0, 0, 0);
    }

    // ---- block-level reduction over the 4 waves (disjoint m-quarters)
#pragma unroll
    for (int r = 0; r < 16; ++r)
        lnom[wid * 1024 + lane * 16 + r] = nom[r];
    den += __shfl_xor(den, 32);
    if (h == 0) lden[wid * 32 + ln] = den;
    __syncthreads();

    const int t   = threadIdx.x;
    const int row = t >> 3;                 // 0..31 (n offset)
    const int d0  = (t & 7) * 4;            // 4 consecutive d per thread
    const int hs  = (row >> 2) & 1;
    const int rs  = (row & 3) | ((row >> 3) << 2);
    float vr[4];
#pragma unroll
    for (int k = 0; k < 4; ++k) {
        const int ls = d0 + k + 32 * hs;
        float v = 0.f;
#pragma unroll
        for (int w = 0; w < 4; ++w) v += lnom[w * 1024 + ls * 16 + rs];
        vr[k] = v;
    }
    const size_t base = (size_t)blockIdx.y * N;
    *reinterpret_cast<float4*>(&pnom[(base + n0 + row) * 32 + d0]) =
        make_float4(vr[0], vr[1], vr[2], vr[3]);
    if (t < 32) {
        float v = lden[t] + lden[32 + t] + lden[64 + t] + lden[96 + t];
        pden[base + n0 + t] = v;
    }
}

// ---------------------------------------------------------------------------
// Reduce over m-chunks and divide.
// ---------------------------------------------------------------------------
__global__ __launch_bounds__(256) void msk_reduce(const float* __restrict__ pnom,
                                                  const float* __restrict__ pden,
                                                  float* __restrict__ out,
                                                  int N, int S) {
    const int t = blockIdx.x * blockDim.x + threadIdx.x;
    if (t >= N * 32) return;
    const int n = t >> 5;
    float nom = 0.f, den = 0.f;
    for (int s = 0; s < S; ++s) {
        nom += pnom[(size_t)s * N * 32 + t];
        den += pden[(size_t)s * N + n];
    }
    out[t] = nom / den;
}

// ---------------------------------------------------------------------------
extern "C" void kernel_launch(void* const* d_in, const int* in_sizes, int n_in,
                              void* d_out, int out_size, void* d_ws, size_t ws_size,
                              hipStream_t stream) {
    const float* X = (const float*)d_in[0];
    const float* Y = (const float*)d_in[1];
    float* out     = (float*)d_out;

    const int N = in_sizes[0] / D;   // 8192
    const int M = in_sizes[1] / D;   // 8192

    char* p = (char*)d_ws;
    ushort* Xb = (ushort*)p; p += (size_t)N * D * sizeof(ushort);
    ushort* Yb = (ushort*)p; p += (size_t)M * D * sizeof(ushort);
    ushort* yT = (ushort*)p; p += (size_t)M * D * sizeof(ushort);
    float*  x2 = (float*)p;  p += (size_t)N * sizeof(float);
    float*  y2 = (float*)p;  p += (size_t)M * sizeof(float);
    size_t used = (size_t)(p - (char*)d_ws);
    used = (used + 255) & ~(size_t)255;

    const size_t per_s = (size_t)N * 33 * sizeof(float);
    int S = 8;                                   // 2048 blocks, 8/CU
    while (S > 1 && used + (size_t)S * per_s > ws_size) S >>= 1;
    const int chunk = M / S;                     // divisible by 256 (4 waves x 64)

    float* pnom = (float*)((char*)d_ws + used);
    float* pden = pnom + (size_t)S * N * 32;

    msk_prep<<<dim3(((N + M) * 4 + 255) / 256), dim3(256), 0, stream>>>(
        X, Y, Xb, Yb, yT, x2, y2, N, M);

    msk_main<<<dim3(N / 32, S), dim3(256), 0, stream>>>(
        Xb, Yb, yT, x2, y2, pnom, pden, N, M, chunk);

    msk_reduce<<<dim3((N * 32 + 255) / 256), dim3(256), 0, stream>>>(
        pnom, pden, out, N, S);
}

// Round 5
// 91.413 us; speedup vs baseline: 1.4223x; 1.2787x over previous
//
#include <hip/hip_runtime.h>
#include <hip/hip_bf16.h>

#define D 32
#define FACTOR (-1.0f / 128.0f)   // -1/(2*8^2)
#define LOG2E  1.44269504088896340736f

typedef __attribute__((ext_vector_type(8)))  short bf16x8;
typedef __attribute__((ext_vector_type(16))) float f32x16;
typedef __attribute__((ext_vector_type(4)))  float f32x4;

#if __has_builtin(__builtin_amdgcn_exp2f)
#define EXP2(x) __builtin_amdgcn_exp2f(x)
#else
#define EXP2(x) exp2f(x)
#endif

__device__ __forceinline__ ushort bfr(float x) {
    __hip_bfloat16 h = __float2bfloat16(x);     // RNE
    return *reinterpret_cast<ushort*>(&h);
}
__device__ __forceinline__ float bf2f(ushort u) {
    uint w = ((uint)u) << 16;
    return *reinterpret_cast<float*>(&w);
}
__device__ __forceinline__ uint pk2(float a, float b) {
    return (uint)bfr(a) | ((uint)bfr(b) << 16);
}

// ---------------------------------------------------------------------------
// Prep: bf16 copies of X and Y, transposed yT[d][m], x2/y2 from ROUNDED
// values. 4 lanes per row, 8 elements per lane.
// ---------------------------------------------------------------------------
__global__ __launch_bounds__(256) void msk_prep(const float* __restrict__ X,
                                                const float* __restrict__ Y,
                                                ushort* __restrict__ Xb,
                                                ushort* __restrict__ Yb,
                                                ushort* __restrict__ yT,
                                                float* __restrict__ x2,
                                                float* __restrict__ y2,
                                                int N, int M) {
    const int t = blockIdx.x * 256 + threadIdx.x;
    const int i = t >> 2;
    const int c = t & 3;
    if (i >= N + M) return;
    const bool isX = (i < N);
    const int r = isX ? i : i - N;
    const float* src = (isX ? X : Y) + (size_t)r * D + c * 8;

    float4 va = *reinterpret_cast<const float4*>(src);
    float4 vb = *reinterpret_cast<const float4*>(src + 4);
    float f[8] = {va.x, va.y, va.z, va.w, vb.x, vb.y, vb.z, vb.w};

    ushort u[8];
    float s = 0.f;
#pragma unroll
    for (int k = 0; k < 8; ++k) {
        u[k] = bfr(f[k]);
        float g = bf2f(u[k]);
        s = fmaf(g, g, s);
    }
    s += __shfl_xor(s, 1);
    s += __shfl_xor(s, 2);

    uint w[4];
#pragma unroll
    for (int q = 0; q < 4; ++q) w[q] = (uint)u[2 * q] | ((uint)u[2 * q + 1] << 16);

    ushort* dstrow = (isX ? Xb : Yb) + (size_t)r * D + c * 8;
    *reinterpret_cast<uint4*>(dstrow) = *reinterpret_cast<const uint4*>(w);

    if (c == 0) (isX ? x2 : y2)[r] = s;

    if (!isX) {
#pragma unroll
        for (int k = 0; k < 8; ++k)
            yT[(size_t)(c * 8 + k) * M + r] = u[k];
    }
}

// ---------------------------------------------------------------------------
// Main fused kernel, flash-style. Block = 4 waves x 32 n = 128 n; all waves
// share the m-stream. Per 64-m step: cooperative coalesced global loads of
// Yb-tile (64x64B) and yT-tile (32x128B) into double-buffered, slot-XOR-
// swizzled LDS; each wave: GEMM1 (2x mfma_32x32x16) -> exp (log2 domain) ->
// pack -> GEMM2 (2x mfma). Reg-staged pipeline: step t+2 loads issued while
// computing step t; one barrier per step. Waves own disjoint n -> direct
// partial writes (no cross-wave reduction).
// ---------------------------------------------------------------------------
__global__ __launch_bounds__(256) void msk_main(const ushort* __restrict__ Xb,
                                                const ushort* __restrict__ Yb,
                                                const ushort* __restrict__ yT,
                                                const float* __restrict__ x2,
                                                const float* __restrict__ y2,
                                                float* __restrict__ pnom,
                                                float* __restrict__ pden,
                                                int N, int M, int chunk) {
    __shared__ uint4 lYb[2][64][4];   // [buf][m-row][16B slot], slot c at c^(r&3)
    __shared__ uint4 lYT[2][32][8];   // [buf][d-row][16B slot], slot s at s^(d&7)

    const int tid  = threadIdx.x;
    const int lane = tid & 63;
    const int wid  = tid >> 6;
    const int h    = lane >> 5;
    const int ln   = lane & 31;
    const int n0   = blockIdx.x * 128 + wid * 32;
    const int m0b  = blockIdx.y * chunk;
    const int ns   = chunk >> 6;                 // 64-m steps

    // cooperative-load roles
    const int rY = tid >> 2, cY = tid & 3;       // Yb: m-row, 16B col
    const int dT = tid >> 3, sT = tid & 7;       // yT: d-row, 16B col

    // x B-fragments: element (h,j) <-> d = 16*ks + 8h + j
    const ushort* xrow = Xb + (size_t)(n0 + ln) * D + h * 8;
    const bf16x8 xf0 = *reinterpret_cast<const bf16x8*>(xrow);
    const bf16x8 xf1 = *reinterpret_cast<const bf16x8*>(xrow + 16);

    const float F2  = FACTOR * LOG2E;
    const float C2  = -2.0f * F2;
    const float xb2 = x2[n0 + ln] * F2;

    f32x16 nom = {};
    float den = 0.f;

    union Fu { uint u[4]; bf16x8 v; };

    uint4 ldYb, ldYT;
    auto issue_loads = [&](int step) {
        const int m = m0b + step * 64;
        ldYb = *(reinterpret_cast<const uint4*>(Yb + (size_t)(m + rY) * D) + cY);
        ldYT = *(reinterpret_cast<const uint4*>(yT + (size_t)dT * M + m) + sT);
    };
    auto stage = [&](int b) {
        lYb[b][rY][cY ^ (rY & 3)] = ldYb;
        lYT[b][dT][sT ^ (dT & 7)] = ldYT;
    };

    issue_loads(0);
    stage(0);
    if (ns > 1) issue_loads(1);

    for (int t = 0; t < ns; ++t) {
        __syncthreads();
        const int b  = t & 1;
        const int m0 = m0b + t * 64;

#pragma unroll
        for (int tA = 0; tA < 2; ++tA) {
            // GEMM1 A-frags from LDS Yb tile rows tA*32+ln
            const int lr = tA * 32 + ln;
            const bf16x8 af0 = *reinterpret_cast<const bf16x8*>(
                &lYb[b][lr][(0 + h) ^ (ln & 3)]);
            const bf16x8 af1 = *reinterpret_cast<const bf16x8*>(
                &lYb[b][lr][(2 + h) ^ (ln & 3)]);

            f32x16 s = {};
            s = __builtin_amdgcn_mfma_f32_32x32x16_bf16(af0, xf0, s, 0, 0, 0);
            s = __builtin_amdgcn_mfma_f32_32x32x16_bf16(af1, xf1, s, 0, 0, 0);
            // s reg r: m = m0 + tA*32 + (r&3) + 8*(r>>2) + 4h ; n = n0 + ln

            const int mt = m0 + tA * 32;
            uint pw[8];
#pragma unroll
            for (int r4 = 0; r4 < 4; ++r4) {
                f32x4 yv = *reinterpret_cast<const f32x4*>(y2 + mt + r4 * 8 + h * 4);
                float kq[4];
#pragma unroll
                for (int q = 0; q < 4; ++q)
                    kq[q] = EXP2(fmaf(s[r4 * 4 + q], C2, fmaf(yv[q], F2, xb2)));
                den += (kq[0] + kq[1]) + (kq[2] + kq[3]);
                pw[r4 * 2 + 0] = pk2(kq[0], kq[1]);
                pw[r4 * 2 + 1] = pk2(kq[2], kq[3]);
            }
            Fu pa0, pa1;
#pragma unroll
            for (int q = 0; q < 4; ++q) { pa0.u[q] = pw[q]; pa1.u[q] = pw[q + 4]; }

            // GEMM2 B-frags from LDS yT tile row ln; slots tA*4 + {0..3}
            const uint2* yr = reinterpret_cast<const uint2*>(&lYT[b][ln][0]);
            const int sw = ln & 7;
            Fu b0, b1;
            *reinterpret_cast<uint2*>(&b0.u[0]) = yr[((tA * 4 + 0) ^ sw) * 2 + h];
            *reinterpret_cast<uint2*>(&b0.u[2]) = yr[((tA * 4 + 1) ^ sw) * 2 + h];
            *reinterpret_cast<uint2*>(&b1.u[0]) = yr[((tA * 4 + 2) ^ sw) * 2 + h];
            *reinterpret_cast<uint2*>(&b1.u[2]) = yr[((tA * 4 + 3) ^ sw) * 2 + h];

            nom = __builtin_amdgcn_mfma_f32_32x32x16_bf16(pa0.v, b0.v, nom, 0, 0, 0);
            nom = __builtin_amdgcn_mfma_f32_32x32x16_bf16(pa1.v, b1.v, nom, 0, 0, 0);
        }

        if (t + 1 < ns) {
            stage((t + 1) & 1);                  // waits only on its own vmcnt
            if (t + 2 < ns) issue_loads(t + 2);  // hide HBM/L2 latency under next compute
        }
    }

    // den: halves hold disjoint m partials for the same n=ln
    den += __shfl_xor(den, 32);

    const size_t base = (size_t)blockIdx.y * N;
#pragma unroll
    for (int r = 0; r < 16; ++r) {
        const int row = (r & 3) + 8 * (r >> 2) + 4 * h;      // n offset
        pnom[(base + n0 + row) * 32 + ln] = nom[r];          // d = ln
    }
    if (h == 0) pden[base + n0 + ln] = den;
}

// ---------------------------------------------------------------------------
// Reduce over m-chunks and divide.
// ---------------------------------------------------------------------------
__global__ __launch_bounds__(256) void msk_reduce(const float* __restrict__ pnom,
                                                  const float* __restrict__ pden,
                                                  float* __restrict__ out,
                                                  int N, int S) {
    const int t = blockIdx.x * blockDim.x + threadIdx.x;
    if (t >= N * 32) return;
    const int n = t >> 5;
    float nom = 0.f, den = 0.f;
    for (int s = 0; s < S; ++s) {
        nom += pnom[(size_t)s * N * 32 + t];
        den += pden[(size_t)s * N + n];
    }
    out[t] = nom / den;
}

// ---------------------------------------------------------------------------
extern "C" void kernel_launch(void* const* d_in, const int* in_sizes, int n_in,
                              void* d_out, int out_size, void* d_ws, size_t ws_size,
                              hipStream_t stream) {
    const float* X = (const float*)d_in[0];
    const float* Y = (const float*)d_in[1];
    float* out     = (float*)d_out;

    const int N = in_sizes[0] / D;   // 8192
    const int M = in_sizes[1] / D;   // 8192

    char* p = (char*)d_ws;
    ushort* Xb = (ushort*)p; p += (size_t)N * D * sizeof(ushort);
    ushort* Yb = (ushort*)p; p += (size_t)M * D * sizeof(ushort);
    ushort* yT = (ushort*)p; p += (size_t)M * D * sizeof(ushort);
    float*  x2 = (float*)p;  p += (size_t)N * sizeof(float);
    float*  y2 = (float*)p;  p += (size_t)M * sizeof(float);
    size_t used = (size_t)(p - (char*)d_ws);
    used = (used + 255) & ~(size_t)255;

    const size_t per_s = (size_t)N * 33 * sizeof(float);
    int S = 16;                                  // 1024 blocks = 4/CU
    while (S > 1 && used + (size_t)S * per_s > ws_size) S >>= 1;
    const int chunk = M / S;                     // 512 -> 8 steps of 64 m

    float* pnom = (float*)((char*)d_ws + used);
    float* pden = pnom + (size_t)S * N * 32;

    msk_prep<<<dim3(((N + M) * 4 + 255) / 256), dim3(256), 0, stream>>>(
        X, Y, Xb, Yb, yT, x2, y2, N, M);

    msk_main<<<dim3(N / 128, S), dim3(256), 0, stream>>>(
        Xb, Yb, yT, x2, y2, pnom, pden, N, M, chunk);

    msk_reduce<<<dim3((N * 32 + 255) / 256), dim3(256), 0, stream>>>(
        pnom, pden, out, N, S);
}